// Round 2
// baseline (488.583 us; speedup 1.0000x reference)
//
#include <hip/hip_runtime.h>
#include <hip/hip_bf16.h>

#define DEVINL __device__ __forceinline__

constexpr int Bb = 8;
constexpr int Nn = 10000;
constexpr int Ff = 256;     // F (K dim of GEMM)
constexpr int Hh = 128;     // H (N dim of GEMM)
constexpr int Ee = 320000;
constexpr int Mm = Bb * Nn; // 80000 GEMM rows

constexpr int GPB = 40;                    // edge-pass workgroups per batch
constexpr int EPG = Ee / GPB;              // 8000 edges per workgroup
constexpr int TW_BLOCKS = (Ff * Hh) / 256; // 128 transpose blocks (fused)
constexpr int SCAP = 160;                  // per-row stage cap (mean 32, ~22 sigma)

typedef __attribute__((ext_vector_type(8))) short short8;
typedef __attribute__((ext_vector_type(4))) float float4v;
typedef __attribute__((ext_vector_type(4))) unsigned short ushort4v;

DEVINL float b2f(unsigned short s) {
    unsigned int u = ((unsigned int)s) << 16;
    float f;
    __builtin_memcpy(&f, &u, 4);
    return f;
}
DEVINL unsigned short f2b(float f) {
    unsigned int u;
    __builtin_memcpy(&u, &f, 4);
    unsigned int r = (u + 0x7fffu + ((u >> 16) & 1u)) >> 16;
    return (unsigned short)r;
}
DEVINL float i2f(int i) {
    float f;
    __builtin_memcpy(&f, &i, 4);
    return f;
}
DEVINL float lo_bf(unsigned int two) {
    unsigned int u = two << 16;
    float f;
    __builtin_memcpy(&f, &u, 4);
    return f;
}
DEVINL float hi_bf(unsigned int two) {
    unsigned int u = two & 0xffff0000u;
    float f;
    __builtin_memcpy(&f, &u, 4);
    return f;
}

// ---------------- K1: per-row histogram (+ fused weight transpose) -----------
// blocks [0, Bb*GPB): histogram; XCD-swizzled (b = raw&7 -> XCD b).
// blocks [Bb*GPB, +TW_BLOCKS): w[K][H] fp32 -> wT[H][K] bf16.
__global__ __launch_bounds__(256) void hist_kernel(const int* __restrict__ rows,
                                                   int* __restrict__ cnt,
                                                   const float* __restrict__ w,
                                                   unsigned short* __restrict__ wT) {
    int t = threadIdx.x;
    if (blockIdx.x >= Bb * GPB) {
        int idx = (blockIdx.x - Bb * GPB) * 256 + t;
        if (idx < Ff * Hh) {
            int h = idx / Ff, k = idx % Ff;
            wT[idx] = f2b(w[(size_t)k * Hh + h]);
        }
        return;
    }
    int raw = blockIdx.x;
    int b = raw & 7;
    int g = raw >> 3;
    const int base = b * Ee + g * EPG;
    int* cb = cnt + b * Nn;
    for (int i = t; i < EPG; i += 256)
        atomicAdd(&cb[rows[base + i]], 1);
}

// ---------------- K2: per-batch exclusive scan (8 independent blocks) --------
// Each batch has exactly Ee edges -> batch b's CSR region is [b*Ee, (b+1)*Ee).
__global__ __launch_bounds__(1024) void scan_kernel(const int* __restrict__ cnt,
                                                    int* __restrict__ off,
                                                    int* __restrict__ cur) {
    __shared__ int wsum[16];
    int b = blockIdx.x;
    int t = threadIdx.x;
    int lane = t & 63, w = t >> 6;
    const int base = b * Nn;
    int local[10];
    int s = 0;
    int r0 = t * 10;
#pragma unroll
    for (int j = 0; j < 10; j++) {
        int r = r0 + j;
        int c = (r < Nn) ? cnt[base + r] : 0;
        local[j] = s;
        s += c;
    }
    // inclusive wave scan of per-thread totals
    int incl = s;
#pragma unroll
    for (int d = 1; d < 64; d <<= 1) {
        int o = __shfl_up(incl, d);
        if (lane >= d) incl += o;
    }
    if (lane == 63) wsum[w] = incl;
    __syncthreads();
    if (w == 0) {
        int v = (lane < 16) ? wsum[lane] : 0;
        int sc = v;
#pragma unroll
        for (int d = 1; d < 16; d <<= 1) {
            int o = __shfl_up(sc, d);
            if (lane >= d) sc += o;
        }
        if (lane < 16) wsum[lane] = sc - v;  // exclusive wave base
    }
    __syncthreads();
    int tbase = b * Ee + wsum[w] + (incl - s);  // exclusive thread base
#pragma unroll
    for (int j = 0; j < 10; j++) {
        int r = r0 + j;
        if (r < Nn) {
            int o = tbase + local[j];
            off[base + r] = o;
            cur[base + r] = o;
        }
    }
}

// ---------------- K3: scatter edges to exact CSR slots -----------------------
// record: .x = col<<8 (byte offset into xw row), .y = fp32 val bits
__global__ __launch_bounds__(256) void scatter_kernel(const int* __restrict__ rows,
                                                      const int* __restrict__ cols,
                                                      const float* __restrict__ vals,
                                                      int* __restrict__ cur,
                                                      int2* __restrict__ csr) {
    int raw = blockIdx.x;
    int b = raw & 7;
    int g = raw >> 3;
    int t = threadIdx.x;
    const int base = b * Ee + g * EPG;
    int* cb = cur + b * Nn;
    for (int i = t; i < EPG; i += 256) {
        int r = rows[base + i];
        int c = cols[base + i];
        float vf = vals[base + i];
        int vb;
        __builtin_memcpy(&vb, &vf, 4);
        int pos = atomicAdd(&cb[r], 1);
        csr[pos] = make_int2(c << 8, vb);
    }
}

// ---------------- fused dropout + GEMM (LDS-staged bf16 MFMA) ----------------
__global__ __launch_bounds__(256, 3) void gemm_kernel(const float* __restrict__ x,
                                                      const float* __restrict__ u,
                                                      const unsigned short* __restrict__ wT,
                                                      unsigned short* __restrict__ xw) {
    __shared__ unsigned short sA[64 * 136];
    __shared__ unsigned short sB[128 * 136];
    int t = threadIdx.x;
    int wave = t >> 6, lane = t & 63;
    int n = lane & 15, q = lane >> 4;
    int m0 = blockIdx.x * 64;

    float4v acc[8];
#pragma unroll
    for (int i = 0; i < 8; i++) acc[i] = {0.f, 0.f, 0.f, 0.f};

    for (int kh = 0; kh < 2; kh++) {
#pragma unroll
        for (int i = 0; i < 8; i++) {
            int idx = t + i * 256;
            int row = idx >> 5;
            int c4 = idx & 31;
            const float* xp = x + (size_t)(m0 + row) * Ff + kh * 128 + c4 * 4;
            const float* up = u + (size_t)(m0 + row) * Ff + kh * 128 + c4 * 4;
            float4 xv = *(const float4*)xp;
            float4 uv = *(const float4*)up;
            ushort4v a;
            a.x = f2b(uv.x > 0.5f ? xv.x * 2.0f : 0.0f);
            a.y = f2b(uv.y > 0.5f ? xv.y * 2.0f : 0.0f);
            a.z = f2b(uv.z > 0.5f ? xv.z * 2.0f : 0.0f);
            a.w = f2b(uv.w > 0.5f ? xv.w * 2.0f : 0.0f);
            *(ushort4v*)(&sA[row * 136 + c4 * 4]) = a;
        }
#pragma unroll
        for (int i = 0; i < 8; i++) {
            int idx = t + i * 256;
            int h = idx >> 4;
            int kc = idx & 15;
            short8 bv = *(const short8*)(wT + (size_t)h * Ff + kh * 128 + kc * 8);
            *(short8*)(&sB[h * 136 + kc * 8]) = bv;
        }
        __syncthreads();
#pragma unroll
        for (int k0 = 0; k0 < 128; k0 += 32) {
            short8 af = *(const short8*)(&sA[(wave * 16 + n) * 136 + k0 + q * 8]);
#pragma unroll
            for (int tt = 0; tt < 8; tt++) {
                short8 bf = *(const short8*)(&sB[(tt * 16 + n) * 136 + k0 + q * 8]);
                acc[tt] = __builtin_amdgcn_mfma_f32_16x16x32_bf16(af, bf, acc[tt], 0, 0, 0);
            }
        }
        __syncthreads();
    }
#pragma unroll
    for (int tt = 0; tt < 8; tt++) {
#pragma unroll
        for (int r = 0; r < 4; r++) {
            int row = m0 + wave * 16 + q * 4 + r;
            int col = tt * 16 + n;
            xw[(size_t)row * Hh + col] = f2b(acc[tt][r]);
        }
    }
}

// ---------------- K5: SpMM, one wave per row (CSR, no sort phases) -----------
// Wave stages its row's edges into LDS (coalesced), then same-address
// ds_read_b64 broadcast per edge: 1 v_add (addr) + 2 unpack + 2 fma per edge.
// Grid 8*2500; b = raw&7 keeps batch b's xw slice (2.56 MB) in XCD b's L2.
__global__ __launch_bounds__(256) void spmm_kernel(const int* __restrict__ off,
                                                   const int* __restrict__ cnt,
                                                   const int2* __restrict__ csr,
                                                   const unsigned short* __restrict__ xw,
                                                   float* __restrict__ out) {
    __shared__ int2 sE[4 * SCAP];
    int raw = blockIdx.x;
    int b = raw & 7;
    int rchunk = raw >> 3;            // 0..2499
    int t = threadIdx.x, w = t >> 6, lane = t & 63;
    int row = rchunk * 4 + w;         // 0..9999
    int gi = b * Nn + row;
    int o0 = off[gi];
    int rc = cnt[gi];
    int cstage = rc < SCAP ? rc : SCAP;
    int2* slot = sE + w * SCAP;
    for (int i = lane; i < cstage; i += 64) slot[i] = csr[o0 + i];
    int c4 = (cstage + 3) & ~3;
    for (int i = cstage + lane; i < c4; i += 64) slot[i] = make_int2(0, 0);
    __syncthreads();

    const char* xwb = (const char*)(xw + (size_t)b * Nn * Hh);
    int lane4 = lane * 4;
    float a0[4], a1[4];
#pragma unroll
    for (int k = 0; k < 4; k++) { a0[k] = 0.f; a1[k] = 0.f; }

    for (int i = 0; i < c4; i += 4) {
#pragma unroll
        for (int k = 0; k < 4; k++) {
            int2 e = slot[i + k];
            unsigned int two = *(const unsigned int*)(xwb + (unsigned)(e.x + lane4));
            float v = i2f(e.y);
            a0[k] += v * lo_bf(two);
            a1[k] += v * hi_bf(two);
        }
    }
    // overflow fallback (rc > SCAP): practically unreachable, kept for safety
    for (int i = SCAP; i < rc; i++) {
        int2 e = csr[o0 + i];
        unsigned int two = *(const unsigned int*)(xwb + (unsigned)(e.x + lane4));
        float v = i2f(e.y);
        a0[0] += v * lo_bf(two);
        a1[0] += v * hi_bf(two);
    }
    float s0 = (a0[0] + a0[1]) + (a0[2] + a0[3]);
    float s1 = (a1[0] + a1[1]) + (a1[2] + a1[3]);
    float2 res;
    res.x = s0;
    res.y = s1;
    *(float2*)(out + ((size_t)b * Nn + row) * Hh + lane * 2) = res;
}

extern "C" void kernel_launch(void* const* d_in, const int* in_sizes, int n_in,
                              void* d_out, int out_size, void* d_ws, size_t ws_size,
                              hipStream_t stream) {
    const float* x    = (const float*)d_in[0]; // fp32 [B,N,F]
    const float* du   = (const float*)d_in[1]; // fp32 [B,N,F]
    const int*   rows = (const int*)d_in[2];   // int32 [B,E]
    const int*   cols = (const int*)d_in[3];   // int32 [B,E]
    const float* vals = (const float*)d_in[4]; // fp32 [B,E]
    const float* w    = (const float*)d_in[5]; // fp32 [F,H]
    float*       out  = (float*)d_out;         // fp32 [B,N,H]

    char* p = (char*)d_ws;
    unsigned short* xw = (unsigned short*)p; p += (size_t)Mm * Hh * 2;   // 20.48 MB
    unsigned short* wT = (unsigned short*)p; p += (size_t)Ff * Hh * 2;   // 64 KB
    int* cnt  = (int*)p; p += (size_t)Mm * 4;                            // 320 KB
    int* off  = (int*)p; p += (size_t)Mm * 4;                            // 320 KB
    int* cur  = (int*)p; p += (size_t)Mm * 4;                            // 320 KB
    int2* csr = (int2*)p; p += (size_t)Bb * Ee * 8;                      // 20.48 MB

    hipMemsetAsync(cnt, 0, (size_t)Mm * 4, stream);
    hist_kernel<<<Bb * GPB + TW_BLOCKS, 256, 0, stream>>>(rows, cnt, w, wT);
    scan_kernel<<<Bb, 1024, 0, stream>>>(cnt, off, cur);
    scatter_kernel<<<Bb * GPB, 256, 0, stream>>>(rows, cols, vals, cur, csr);
    gemm_kernel<<<Mm / 64, 256, 0, stream>>>(x, du, wT, xw);
    spmm_kernel<<<Bb * 2500, 256, 0, stream>>>(off, cnt, csr, xw, out);
}

// Round 3
// 288.913 us; speedup vs baseline: 1.6911x; 1.6911x over previous
//
#include <hip/hip_runtime.h>
#include <hip/hip_bf16.h>

#define DEVINL __device__ __forceinline__

constexpr int Bb = 8;
constexpr int Nn = 10000;
constexpr int Ff = 256;     // F (K dim of GEMM)
constexpr int Hh = 128;     // H (N dim of GEMM)
constexpr int Ee = 320000;
constexpr int Mm = Bb * Nn; // 80000 GEMM rows

constexpr int CHUNK = 64;                     // rows per bucket
constexpr int NCH = (Nn + CHUNK - 1) / CHUNK; // 157 buckets/batch
constexpr int CAP = 2560;                     // bucket capacity (mean 2048, 11 sigma)
constexpr int GPB = 80;                       // binning workgroups per batch
constexpr int EPG = Ee / GPB;                 // 4000 edges per workgroup (32 KB LDS)
constexpr int TW_BLOCKS = (Ff * Hh) / 256;    // 128 transpose blocks (fused)

typedef __attribute__((ext_vector_type(8))) short short8;
typedef __attribute__((ext_vector_type(4))) float float4v;
typedef __attribute__((ext_vector_type(4))) unsigned short ushort4v;

DEVINL unsigned short f2b(float f) {
    unsigned int u;
    __builtin_memcpy(&u, &f, 4);
    unsigned int r = (u + 0x7fffu + ((u >> 16) & 1u)) >> 16;
    return (unsigned short)r;
}
DEVINL float i2f(int i) {
    float f;
    __builtin_memcpy(&f, &i, 4);
    return f;
}
DEVINL float lo_bf(unsigned int two) {
    unsigned int u = two << 16;
    float f;
    __builtin_memcpy(&f, &u, 4);
    return f;
}
DEVINL float hi_bf(unsigned int two) {
    unsigned int u = two & 0xffff0000u;
    float f;
    __builtin_memcpy(&f, &u, 4);
    return f;
}

// ---------------- K1: LDS-staged bucket sort (+ fused weight transpose) ------
// Each workgroup: stage 4000 edges -> LDS histogram over 157 buckets -> scan
// -> LDS bucket-sort -> write each bucket's run CONTIGUOUSLY (mean 200 B/run).
// Kills the 5.7x write amplification of per-row scatter (117 MB -> ~25 MB).
// XCD-swizzled: b = raw&7 -> batch b's cur/bkt stay on XCD b's L2.
// record: .x = (row&63)<<26 | col<<8 | bucket, .y = fp32 val bits
__global__ __launch_bounds__(256) void bucket2_kernel(const int* __restrict__ rows,
                                                      const int* __restrict__ cols,
                                                      const float* __restrict__ vals,
                                                      int* __restrict__ cur,
                                                      int2* __restrict__ bkt,
                                                      const float* __restrict__ w,
                                                      unsigned short* __restrict__ wT) {
    int t = threadIdx.x;
    if (blockIdx.x >= Bb * GPB) {
        int idx = (blockIdx.x - Bb * GPB) * 256 + t;
        if (idx < Ff * Hh) {
            int h = idx / Ff, k = idx % Ff;
            wT[idx] = f2b(w[(size_t)k * Hh + h]);
        }
        return;
    }
    __shared__ int2 sedge[EPG];            // 32 KB sorted edges
    __shared__ int lcnt[NCH];
    __shared__ int lofs[NCH];
    __shared__ int lcur[NCH];
    __shared__ int gall[NCH];
    __shared__ int wsum[4];
    int raw = blockIdx.x;
    int b = raw & 7;
    int g = raw >> 3;
    const int base = b * Ee + g * EPG;

    for (int j = t; j < NCH; j += 256) lcnt[j] = 0;
    __syncthreads();
    for (int i = t; i < EPG; i += 256)
        atomicAdd(&lcnt[rows[base + i] >> 6], 1);
    __syncthreads();
    // exclusive scan over 157 buckets (256-thread, one pass)
    {
        int lane = t & 63, wv = t >> 6;
        int v = (t < NCH) ? lcnt[t] : 0;
        int incl = v;
#pragma unroll
        for (int d = 1; d < 64; d <<= 1) {
            int o = __shfl_up(incl, d);
            if (lane >= d) incl += o;
        }
        if (lane == 63) wsum[wv] = incl;
        __syncthreads();
        if (t == 0) {
            int s = 0;
#pragma unroll
            for (int k = 0; k < 4; k++) { int x = wsum[k]; wsum[k] = s; s += x; }
        }
        __syncthreads();
        if (t < NCH) {
            int ex = incl - v + wsum[wv];
            lofs[t] = ex;
            lcur[t] = ex;
        }
    }
    __syncthreads();
    // reserve global bucket space; gall[j] = gbase - lofs[j] so slot = gall[j]+i
    for (int j = t; j < NCH; j += 256) {
        int gb = atomicAdd(&cur[b * NCH + j], lcnt[j]);
        gall[j] = gb - lofs[j];
    }
    __syncthreads();
    // bucket-sort edges into LDS
    for (int i = t; i < EPG; i += 256) {
        int r = rows[base + i];
        int c = cols[base + i];
        float vf = vals[base + i];
        int vb;
        __builtin_memcpy(&vb, &vf, 4);
        int bk = r >> 6;
        int p = atomicAdd(&lcur[bk], 1);
        sedge[p] = make_int2(((r & 63) << 26) | (c << 8) | bk, vb);
    }
    __syncthreads();
    // contiguous run writes
    for (int i = t; i < EPG; i += 256) {
        int2 e = sedge[i];
        int j = e.x & 0xff;
        int slot = gall[j] + i;
        if (slot < CAP)
            bkt[(size_t)(b * NCH + j) * CAP + slot] = e;
    }
}

// ---------------- fused dropout + GEMM (LDS-staged bf16 MFMA) ----------------
__global__ __launch_bounds__(256, 3) void gemm_kernel(const float* __restrict__ x,
                                                      const float* __restrict__ u,
                                                      const unsigned short* __restrict__ wT,
                                                      unsigned short* __restrict__ xw) {
    __shared__ unsigned short sA[64 * 136];
    __shared__ unsigned short sB[128 * 136];
    int t = threadIdx.x;
    int wave = t >> 6, lane = t & 63;
    int n = lane & 15, q = lane >> 4;
    int m0 = blockIdx.x * 64;

    float4v acc[8];
#pragma unroll
    for (int i = 0; i < 8; i++) acc[i] = {0.f, 0.f, 0.f, 0.f};

    for (int kh = 0; kh < 2; kh++) {
#pragma unroll
        for (int i = 0; i < 8; i++) {
            int idx = t + i * 256;
            int row = idx >> 5;
            int c4 = idx & 31;
            const float* xp = x + (size_t)(m0 + row) * Ff + kh * 128 + c4 * 4;
            const float* up = u + (size_t)(m0 + row) * Ff + kh * 128 + c4 * 4;
            float4 xv = *(const float4*)xp;
            float4 uv = *(const float4*)up;
            ushort4v a;
            a.x = f2b(uv.x > 0.5f ? xv.x * 2.0f : 0.0f);
            a.y = f2b(uv.y > 0.5f ? xv.y * 2.0f : 0.0f);
            a.z = f2b(uv.z > 0.5f ? xv.z * 2.0f : 0.0f);
            a.w = f2b(uv.w > 0.5f ? xv.w * 2.0f : 0.0f);
            *(ushort4v*)(&sA[row * 136 + c4 * 4]) = a;
        }
#pragma unroll
        for (int i = 0; i < 8; i++) {
            int idx = t + i * 256;
            int h = idx >> 4;
            int kc = idx & 15;
            short8 bv = *(const short8*)(wT + (size_t)h * Ff + kh * 128 + kc * 8);
            *(short8*)(&sB[h * 136 + kc * 8]) = bv;
        }
        __syncthreads();
#pragma unroll
        for (int k0 = 0; k0 < 128; k0 += 32) {
            short8 af = *(const short8*)(&sA[(wave * 16 + n) * 136 + k0 + q * 8]);
#pragma unroll
            for (int tt = 0; tt < 8; tt++) {
                short8 bf = *(const short8*)(&sB[(tt * 16 + n) * 136 + k0 + q * 8]);
                acc[tt] = __builtin_amdgcn_mfma_f32_16x16x32_bf16(af, bf, acc[tt], 0, 0, 0);
            }
        }
        __syncthreads();
    }
#pragma unroll
    for (int tt = 0; tt < 8; tt++) {
#pragma unroll
        for (int r = 0; r < 4; r++) {
            int row = m0 + wave * 16 + q * 4 + r;
            int col = tt * 16 + n;
            xw[(size_t)row * Hh + col] = f2b(acc[tt][r]);
        }
    }
}

// ---------------- K3: SpMM — LDS row-sort + broadcast-read MLP ---------------
// Phases 1-3 (cheap: ~128 wave-LDS-ops/block): histogram 64 rows, scan,
// scatter into row-sorted ssort. Phase 4: per row, wave walks edges via
// wave-uniform ds_read_b64 broadcast (replaces the 2x v_readlane + lane
// staging + pad-to-64 of round 1): 1 v_add (pre-masked col byte offset) +
// 1 dword gather (L2, XCD-local) + 2 unpack + 2 fma per edge.
__global__ __launch_bounds__(256) void spmm_kernel(const int* __restrict__ cur,
                                                   const int2* __restrict__ bkt,
                                                   const unsigned short* __restrict__ xw,
                                                   float* __restrict__ out) {
    __shared__ int2 ssort[CAP];       // 20.5 KB sorted edges
    __shared__ int rh[CHUNK];
    __shared__ int roff[CHUNK];
    __shared__ int rcur[CHUNK];
    int raw = blockIdx.x;
    int blk = (raw & 7) * NCH + (raw >> 3);   // batch b -> XCD b
    int b = blk / NCH, ch = blk % NCH;
    int t = threadIdx.x, w = t >> 6, lane = t & 63;

    if (t < CHUNK) rh[t] = 0;
    __syncthreads();
    int cnt = cur[blk];
    if (cnt > CAP) cnt = CAP;
    const int2* pe = bkt + (size_t)blk * CAP;

    for (int i = t; i < cnt; i += 256)
        atomicAdd(&rh[((unsigned)pe[i].x) >> 26], 1);
    __syncthreads();
    if (w == 0) {
        int v = rh[lane];
        int s = v;
#pragma unroll
        for (int d = 1; d < 64; d <<= 1) {
            int o = __shfl_up(s, d);
            if (lane >= d) s += o;
        }
        roff[lane] = s - v;
        rcur[lane] = s - v;
    }
    __syncthreads();
    for (int i = t; i < cnt; i += 256) {
        int2 e = pe[i];
        int p = atomicAdd(&rcur[((unsigned)e.x) >> 26], 1);
        ssort[p] = make_int2(e.x & 0x3FFF00, e.y);   // col byte-offset only
    }
    __syncthreads();

    const char* xwb = (const char*)(xw + (size_t)b * Nn * Hh);
    int lane4 = lane * 4;
    for (int rr = 0; rr < 16; rr++) {
        int rl = w * 16 + rr;
        int r = ch * CHUNK + rl;
        if (r >= Nn) break;
        int off = roff[rl];
        int rcnt = rh[rl];

        float a0[4], a1[4];
#pragma unroll
        for (int k = 0; k < 4; k++) { a0[k] = 0.f; a1[k] = 0.f; }

        int mn = rcnt & ~3;
        for (int i = 0; i < mn; i += 4) {
#pragma unroll
            for (int k = 0; k < 4; k++) {
                int2 e = ssort[off + i + k];
                unsigned int two = *(const unsigned int*)(xwb + (unsigned)(e.x + lane4));
                float v = i2f(e.y);
                a0[k] += v * lo_bf(two);
                a1[k] += v * hi_bf(two);
            }
        }
        for (int i = mn; i < rcnt; i++) {
            int2 e = ssort[off + i];
            unsigned int two = *(const unsigned int*)(xwb + (unsigned)(e.x + lane4));
            float v = i2f(e.y);
            a0[i - mn] += v * lo_bf(two);
            a1[i - mn] += v * hi_bf(two);
        }
        float s0 = (a0[0] + a0[1]) + (a0[2] + a0[3]);
        float s1 = (a1[0] + a1[1]) + (a1[2] + a1[3]);
        float2 res;
        res.x = s0;
        res.y = s1;
        *(float2*)(out + ((size_t)b * Nn + r) * Hh + lane * 2) = res;
    }
}

extern "C" void kernel_launch(void* const* d_in, const int* in_sizes, int n_in,
                              void* d_out, int out_size, void* d_ws, size_t ws_size,
                              hipStream_t stream) {
    const float* x    = (const float*)d_in[0]; // fp32 [B,N,F]
    const float* du   = (const float*)d_in[1]; // fp32 [B,N,F]
    const int*   rows = (const int*)d_in[2];   // int32 [B,E]
    const int*   cols = (const int*)d_in[3];   // int32 [B,E]
    const float* vals = (const float*)d_in[4]; // fp32 [B,E]
    const float* w    = (const float*)d_in[5]; // fp32 [F,H]
    float*       out  = (float*)d_out;         // fp32 [B,N,H]

    char* p = (char*)d_ws;
    unsigned short* xw = (unsigned short*)p; p += (size_t)Mm * Hh * 2;   // 20.48 MB
    unsigned short* wT = (unsigned short*)p; p += (size_t)Ff * Hh * 2;   // 64 KB
    int* cur   = (int*)p; p += (size_t)Bb * NCH * 4;                     // 5 KB
    int2* bkt  = (int2*)p; p += (size_t)Bb * NCH * CAP * 8;              // 25.7 MB

    hipMemsetAsync(cur, 0, (size_t)Bb * NCH * 4, stream);
    bucket2_kernel<<<Bb * GPB + TW_BLOCKS, 256, 0, stream>>>(rows, cols, vals, cur, bkt, w, wT);
    gemm_kernel<<<Mm / 64, 256, 0, stream>>>(x, du, wT, xw);
    spmm_kernel<<<Bb * NCH, 256, 0, stream>>>(cur, bkt, xw, out);
}